// Round 6
// baseline (155.148 us; speedup 1.0000x reference)
//
#include <hip/hip_runtime.h>
#include <math.h>

#define F 128
#define OUT 128

typedef unsigned short ushort_t;
typedef __attribute__((ext_vector_type(8))) short bfrag;   // 8 bf16
typedef __attribute__((ext_vector_type(4))) float ffrag;   // 4 fp32 acc
typedef __attribute__((ext_vector_type(2))) float fx2;     // 2 fp32

__device__ __forceinline__ float bf_lo(unsigned int u) {
    return __uint_as_float(u << 16);
}
__device__ __forceinline__ float bf_hi(unsigned int u) {
    return __uint_as_float(u & 0xffff0000u);
}
__device__ __forceinline__ ushort_t f2bf(float f) {
    unsigned int x = __float_as_uint(f);
    unsigned int r = x + 0x7fffu + ((x >> 16) & 1u);
    return (ushort_t)(r >> 16);
}
__device__ __forceinline__ unsigned pk2(float lo, float hi) {
    return (unsigned)f2bf(lo) | ((unsigned)f2bf(hi) << 16);
}

// DPP rotate-add within a 16-lane row (VALU, no LDS pipe).
// row_ror:N ctrl = 0x120+N. Double-evaluates x: use with plain lvalues only.
#define DPP_ADD(x, ctrl) \
    ((x) + __int_as_float(__builtin_amdgcn_update_dpp( \
        0, __float_as_int(x), (ctrl), 0xf, 0xf, true)))

// ---------------------------------------------------------------------------
// srcpack row layout (256 B per node, interleaved per lane):
//   lane fl (features 4fl..4fl+3) reads ONE uint2 at byte 8*fl:
//     .x = 4 bytes e_src  (e5m2 "bf8"): exp(2*proj_src) features 4fl..4fl+3
//     .y = 4 bytes feat   (e4m3 fp8):   features 4fl..4fl+3
// -> 256 gathered bytes per edge (was 384), single load per lane per edge.
// ---------------------------------------------------------------------------

// ---------------------------------------------------------------------------
// prep: heterogeneous grid.
//  part0: feat fp32 -> abig[:, :128] bf16 + srcpack fp8 e4m3 slots (HW cvt).
//  part1: btp[j*128+k] = bf16(B[k][j]), B = [w1[:F] | w1[F:]] cols j=0..255.
//  part2: btf[j*256+k] = bf16(wf[k][j]), j=0..127.
//  part3: rowptr (dst sorted).
// ---------------------------------------------------------------------------
__global__ __launch_bounds__(256) void prep_kernel(
    const float* __restrict__ feat, const float* __restrict__ w1,
    const float* __restrict__ wf, const int* __restrict__ dst,
    ushort_t* __restrict__ abig, ushort_t* __restrict__ srcpack,
    ushort_t* __restrict__ btp, ushort_t* __restrict__ btf,
    int* __restrict__ row_ptr, int n, int e, int nb0, int nb1, int nb2)
{
    const int b = blockIdx.x, t = threadIdx.x;
    if (b < nb0) {
        int i = b * 256 + t;
        if (i >= n * 16) return;
        int row = i >> 4, c = (i & 15) * 8;
        float4 a = *(const float4*)(feat + (size_t)row * F + c);
        float4 bb = *(const float4*)(feat + (size_t)row * F + c + 4);
        unsigned p0 = pk2(a.x, a.y), p1 = pk2(a.z, a.w);
        unsigned p2 = pk2(bb.x, bb.y), p3 = pk2(bb.z, bb.w);
        *(uint4*)(abig + (size_t)row * 256 + c) = make_uint4(p0, p1, p2, p3);
        // fp8 e4m3 encode (HW): features c..c+3 -> lane c/4 slot (byte 2c+4),
        // features c+4..c+7 -> lane c/4+1 slot (byte 2c+12).
        unsigned w01 = (unsigned)__builtin_amdgcn_cvt_pk_fp8_f32(a.x, a.y, 0, false);
        w01 = (unsigned)__builtin_amdgcn_cvt_pk_fp8_f32(a.z, a.w, (int)w01, true);
        unsigned w23 = (unsigned)__builtin_amdgcn_cvt_pk_fp8_f32(bb.x, bb.y, 0, false);
        w23 = (unsigned)__builtin_amdgcn_cvt_pk_fp8_f32(bb.z, bb.w, (int)w23, true);
        char* rb = (char*)srcpack + (size_t)row * 256;
        *(unsigned*)(rb + c * 2 + 4) = w01;
        *(unsigned*)(rb + c * 2 + 12) = w23;
    } else if (b < nb0 + nb1) {
        int idx = (b - nb0) * 256 + t;                 // 0..32767
        int j = idx >> 7, k = idx & 127;
        float v = (j < F) ? w1[(size_t)k * F + j]
                          : w1[(size_t)(F + k) * F + (j - F)];
        btp[idx] = f2bf(v);
    } else if (b < nb0 + nb1 + nb2) {
        int idx = (b - nb0 - nb1) * 256 + t;           // 0..32767
        int j = idx >> 8, k = idx & 255;
        btf[idx] = f2bf(wf[(size_t)k * F + j]);
    } else {
        int i = (b - nb0 - nb1 - nb2) * 256 + t;
        if (i >= e) return;
        int d = dst[i];
        int prev = (i == 0) ? -1 : dst[i - 1];
        for (int v = prev + 1; v <= d; ++v) row_ptr[v] = i;
        if (i == e - 1) {
            for (int v = d + 1; v <= n; ++v) row_ptr[v] = e;
        }
    }
}

// ---------------------------------------------------------------------------
// G1 (proj): C[n x 256] = abig_feat(bf16) @ btp, epilogue exp(2*(c+bias)).
// Block = 64 rows x 256 cols, 4 waves (wave w: cols 64w..64w+63).
// cols<128 -> e_dst (+b1) bf16; cols>=128 -> srcpack es slots as e5m2 (bf8).
// ---------------------------------------------------------------------------
#define PST 136
__global__ __launch_bounds__(256) void proj_gemm_kernel(
    const ushort_t* __restrict__ abig, const ushort_t* __restrict__ btp,
    const float* __restrict__ b1, ushort_t* __restrict__ e_dst,
    ushort_t* __restrict__ srcpack, int n)
{
    __shared__ ushort_t As[64 * PST];        // 17408 B
    __shared__ ushort_t Ep[4][16 * 80];      // 10240 B
    const int t = threadIdx.x;
    const int wv = t >> 6, lane = t & 63;
    const int lm = lane & 15, quad = lane >> 4;
    const int row0 = blockIdx.x * 64, col0 = wv * 64;

#pragma unroll
    for (int k = 0; k < 4; ++k) {            // 64 rows x 16 uint4, coalesced
        int l = k * 256 + t;
        int r = l >> 4, ch = l & 15;
        uint4 d = make_uint4(0, 0, 0, 0);
        if (row0 + r < n) d = *(const uint4*)(abig + (size_t)(row0 + r) * 256 + ch * 8);
        *(uint4*)(As + r * PST + ch * 8) = d;
    }
    __syncthreads();

    bfrag bfr[4][4];
#pragma unroll
    for (int ks = 0; ks < 4; ++ks)
#pragma unroll
        for (int ni = 0; ni < 4; ++ni)
            bfr[ks][ni] = *(const bfrag*)(btp + (size_t)(col0 + ni * 16 + lm) * 128
                                          + ks * 32 + quad * 8);

    ffrag acc[4][4];
#pragma unroll
    for (int mi = 0; mi < 4; ++mi)
#pragma unroll
        for (int ni = 0; ni < 4; ++ni) acc[mi][ni] = (ffrag){0.f, 0.f, 0.f, 0.f};

#pragma unroll
    for (int ks = 0; ks < 4; ++ks)
#pragma unroll
        for (int mi = 0; mi < 4; ++mi) {
            bfrag af = *(const bfrag*)(As + (mi * 16 + lm) * PST + ks * 32 + quad * 8);
#pragma unroll
            for (int ni = 0; ni < 4; ++ni)
                acc[mi][ni] = __builtin_amdgcn_mfma_f32_16x16x32_bf16(
                    af, bfr[ks][ni], acc[mi][ni], 0, 0, 0);
        }

    float bias[4];
#pragma unroll
    for (int ni = 0; ni < 4; ++ni)
        bias[ni] = (col0 < F) ? b1[col0 + ni * 16 + lm] : 0.f;

#pragma unroll
    for (int mi = 0; mi < 4; ++mi) {
        // compute-layout write into per-wave patch (conflict-free)
#pragma unroll
        for (int ni = 0; ni < 4; ++ni)
#pragma unroll
            for (int r = 0; r < 4; ++r)
                Ep[wv][(quad * 4 + r) * 80 + ni * 16 + lm] =
                    f2bf(__expf(2.f * (acc[mi][ni][r] + bias[ni])));
        // coalesced read-out: 2 passes x 8 rows x 8 lanes x 16B
#pragma unroll
        for (int ps = 0; ps < 2; ++ps) {
            int rl = ps * 8 + (lane >> 3), co = (lane & 7) * 8;
            uint4 vv = *(const uint4*)(&Ep[wv][rl * 80 + co]);
            int grow = row0 + mi * 16 + rl;
            if (grow < n) {
                if (col0 < F) {
                    *(uint4*)(e_dst + (size_t)grow * F + col0 + co) = vv;
                } else {
                    int f0 = col0 - F + co;   // multiple of 8
                    // es bf16 -> e5m2 (bf8), features f0..f0+3 and f0+4..f0+7
                    unsigned b0 = (unsigned)__builtin_amdgcn_cvt_pk_bf8_f32(
                        bf_lo(vv.x), bf_hi(vv.x), 0, false);
                    b0 = (unsigned)__builtin_amdgcn_cvt_pk_bf8_f32(
                        bf_lo(vv.y), bf_hi(vv.y), (int)b0, true);
                    unsigned b1v = (unsigned)__builtin_amdgcn_cvt_pk_bf8_f32(
                        bf_lo(vv.z), bf_hi(vv.z), 0, false);
                    b1v = (unsigned)__builtin_amdgcn_cvt_pk_bf8_f32(
                        bf_lo(vv.w), bf_hi(vv.w), (int)b1v, true);
                    char* rb = (char*)srcpack + (size_t)grow * 256;
                    *(unsigned*)(rb + f0 * 2) = b0;       // lane f0/4 es slot
                    *(unsigned*)(rb + f0 * 2 + 8) = b1v;  // lane f0/4+1 es slot
                }
            }
        }
    }
}

// ---------------------------------------------------------------------------
// K2: fused score+softmax+aggregate. One 32-lane half-wave per node; per
// edge: ONE uint2 gather per lane (256 B/row: es e5m2 + feat e4m3, HW
// decode). Pair-rcp score (2 rcp/edge/lane: w_a/A + w_b/B =
// (w_a*B+w_b*A)*rcp(A*B), A,B>=1), DPP reduce, static softmax bound
// M = b2 + sum|w2|. Writes neigh bf16 to abig[:, 128:].
// ---------------------------------------------------------------------------
__global__ __launch_bounds__(256) void fused_kernel(
    const ushort_t* __restrict__ e_dst, const ushort_t* __restrict__ srcpack,
    const int* __restrict__ src, const int* __restrict__ row_ptr,
    const float* __restrict__ w2, ushort_t* __restrict__ abig, int n)
{
    const int v = (int)((blockIdx.x * 256u + threadIdx.x) >> 5);
    const int fl = threadIdx.x & 31;
    const int sbase = threadIdx.x & 32;

    const float4 wv4 = ((const float4*)w2)[fl];
    const float w0 = wv4.x, w1_ = wv4.y, w2_ = wv4.z, w3_ = wv4.w;
    float sw = w0 + w1_ + w2_ + w3_;
    float aw = fabsf(w0) + fabsf(w1_) + fabsf(w2_) + fabsf(w3_);
#pragma unroll
    for (int off = 16; off; off >>= 1) {
        sw += __shfl_xor(sw, off, 64);
        aw += __shfl_xor(aw, off, 64);
    }
    const float K = sw - aw;           // score - M = K - 2*pv  (always <= 0)
    const float L2E = 1.4426950408889634f;
    const float K2 = K * L2E;          // g = exp2(K2 - 2*L2E*p)

    if (v >= n) return;
    const int begin = row_ptr[v], end = row_ptr[v + 1];

    const uint2 ud = *(const uint2*)(e_dst + (size_t)v * F + fl * 4);
    const float ea0 = bf_lo(ud.x), ea1 = bf_hi(ud.x);
    const float ea2 = bf_lo(ud.y), ea3 = bf_hi(ud.y);

    const uint2* __restrict__ sp = (const uint2*)srcpack + fl;  // row = 32 uint2

    float s = 0.f, a0 = 0.f, a1 = 0.f, a2 = 0.f, a3 = 0.f;

    for (int cb = begin; cb < end; cb += 32) {
        const int clen = min(32, end - cb);
        const int sv = (fl < clen) ? src[cb + fl] : 0;
        int jj = 0;
        for (; jj + 4 <= clen; jj += 4) {
            uint2 u[4];
#pragma unroll
            for (int q = 0; q < 4; ++q) {
                const int sq = __shfl(sv, sbase + jj + q, 64);
                u[q] = sp[(size_t)sq * 32];
            }
            float p[4];
#pragma unroll
            for (int q = 0; q < 4; ++q) {
                fx2 eslo = __builtin_amdgcn_cvt_pk_f32_bf8((int)u[q].x, false);
                fx2 eshi = __builtin_amdgcn_cvt_pk_f32_bf8((int)u[q].x, true);
                float A = fmaf(ea0, eslo[0], 1.f);
                float B = fmaf(ea1, eslo[1], 1.f);
                float C = fmaf(ea2, eshi[0], 1.f);
                float D = fmaf(ea3, eshi[1], 1.f);
                float nAB = fmaf(w0, B, w1_ * A);
                float nCD = fmaf(w2_, D, w3_ * C);
                float rAB = __builtin_amdgcn_rcpf(A * B);
                float rCD = __builtin_amdgcn_rcpf(C * D);
                p[q] = fmaf(nAB, rAB, nCD * rCD);
            }
#pragma unroll
            for (int q = 0; q < 4; ++q) {
                p[q] = DPP_ADD(p[q], 0x121);     // row_ror:1
                p[q] = DPP_ADD(p[q], 0x122);     // row_ror:2
                p[q] = DPP_ADD(p[q], 0x124);     // row_ror:4
                p[q] = DPP_ADD(p[q], 0x128);     // row_ror:8
                p[q] += __shfl_xor(p[q], 16, 64);
            }
            float g[4];
#pragma unroll
            for (int q = 0; q < 4; ++q)
                g[q] = exp2f(fmaf(-2.f * L2E, p[q], K2));
            s += (g[0] + g[1]) + (g[2] + g[3]);
#pragma unroll
            for (int q = 0; q < 4; ++q) {
                fx2 lo = __builtin_amdgcn_cvt_pk_f32_fp8((int)u[q].y, false);
                fx2 hi = __builtin_amdgcn_cvt_pk_f32_fp8((int)u[q].y, true);
                a0 = fmaf(g[q], lo[0], a0);
                a1 = fmaf(g[q], lo[1], a1);
                a2 = fmaf(g[q], hi[0], a2);
                a3 = fmaf(g[q], hi[1], a3);
            }
        }
        for (; jj < clen; ++jj) {
            const int s0 = __shfl(sv, sbase + jj, 64);
            const uint2 u0 = sp[(size_t)s0 * 32];
            fx2 eslo = __builtin_amdgcn_cvt_pk_f32_bf8((int)u0.x, false);
            fx2 eshi = __builtin_amdgcn_cvt_pk_f32_bf8((int)u0.x, true);
            float A = fmaf(ea0, eslo[0], 1.f);
            float B = fmaf(ea1, eslo[1], 1.f);
            float C = fmaf(ea2, eshi[0], 1.f);
            float D = fmaf(ea3, eshi[1], 1.f);
            float nAB = fmaf(w0, B, w1_ * A);
            float nCD = fmaf(w2_, D, w3_ * C);
            float rAB = __builtin_amdgcn_rcpf(A * B);
            float rCD = __builtin_amdgcn_rcpf(C * D);
            float p0 = fmaf(nAB, rAB, nCD * rCD);
            p0 = DPP_ADD(p0, 0x121);
            p0 = DPP_ADD(p0, 0x122);
            p0 = DPP_ADD(p0, 0x124);
            p0 = DPP_ADD(p0, 0x128);
            p0 += __shfl_xor(p0, 16, 64);
            const float g0 = exp2f(fmaf(-2.f * L2E, p0, K2));
            s += g0;
            fx2 lo = __builtin_amdgcn_cvt_pk_f32_fp8((int)u0.y, false);
            fx2 hi = __builtin_amdgcn_cvt_pk_f32_fp8((int)u0.y, true);
            a0 = fmaf(g0, lo[0], a0);
            a1 = fmaf(g0, lo[1], a1);
            a2 = fmaf(g0, hi[0], a2);
            a3 = fmaf(g0, hi[1], a3);
        }
    }

    const float inv = (end > begin) ? 1.f / s : 0.f;
    ushort4 o = make_ushort4(f2bf(a0 * inv), f2bf(a1 * inv),
                             f2bf(a2 * inv), f2bf(a3 * inv));
    *(ushort4*)(abig + (size_t)v * 256 + 128 + fl * 4) = o;
}

// ---------------------------------------------------------------------------
// G2 (out): out[n x 128] = abig(bf16, K=256) @ btf + bf.
// Block = 64 rows x 128 cols, 4 waves (wave w: cols 32w..32w+31).
// ---------------------------------------------------------------------------
#define OST 280
__global__ __launch_bounds__(256) void out_gemm_kernel(
    const ushort_t* __restrict__ abig, const ushort_t* __restrict__ btf,
    const float* __restrict__ bfv, float* __restrict__ out, int n)
{
    __shared__ ushort_t As[64 * OST];        // 35840 B
    const int t = threadIdx.x;
    const int wv = t >> 6, lane = t & 63;
    const int lm = lane & 15, quad = lane >> 4;
    const int row0 = blockIdx.x * 64, col0 = wv * 32;

#pragma unroll
    for (int k = 0; k < 8; ++k) {            // 64 rows x 32 uint4, coalesced
        int l = k * 256 + t;
        int r = l >> 5, ch = l & 31;
        uint4 d = make_uint4(0, 0, 0, 0);
        if (row0 + r < n) d = *(const uint4*)(abig + (size_t)(row0 + r) * 256 + ch * 8);
        *(uint4*)(As + r * OST + ch * 8) = d;
    }
    __syncthreads();

    bfrag bfr[8][2];
#pragma unroll
    for (int ks = 0; ks < 8; ++ks)
#pragma unroll
        for (int ni = 0; ni < 2; ++ni)
            bfr[ks][ni] = *(const bfrag*)(btf + (size_t)(col0 + ni * 16 + lm) * 256
                                          + ks * 32 + quad * 8);

    ffrag acc[4][2];
#pragma unroll
    for (int mi = 0; mi < 4; ++mi)
#pragma unroll
        for (int ni = 0; ni < 2; ++ni) acc[mi][ni] = (ffrag){0.f, 0.f, 0.f, 0.f};

#pragma unroll
    for (int ks = 0; ks < 8; ++ks)
#pragma unroll
        for (int mi = 0; mi < 4; ++mi) {
            bfrag af = *(const bfrag*)(As + (mi * 16 + lm) * OST + ks * 32 + quad * 8);
#pragma unroll
            for (int ni = 0; ni < 2; ++ni)
                acc[mi][ni] = __builtin_amdgcn_mfma_f32_16x16x32_bf16(
                    af, bfr[ks][ni], acc[mi][ni], 0, 0, 0);
        }

#pragma unroll
    for (int ni = 0; ni < 2; ++ni) {
        const int j = col0 + ni * 16 + lm;
        const float bb = bfv[j];
#pragma unroll
        for (int mi = 0; mi < 4; ++mi)
#pragma unroll
            for (int r = 0; r < 4; ++r) {
                int grow = row0 + mi * 16 + quad * 4 + r;
                if (grow < n) out[(size_t)grow * OUT + j] = acc[mi][ni][r] + bb;
            }
    }
}

// ---------------------------------------------------------------------------
extern "C" void kernel_launch(void* const* d_in, const int* in_sizes, int n_in,
                              void* d_out, int out_size, void* d_ws, size_t ws_size,
                              hipStream_t stream)
{
    const float* feat = (const float*)d_in[0];
    const int*   src  = (const int*)d_in[1];
    const int*   dst  = (const int*)d_in[2];
    const float* w1   = (const float*)d_in[3];
    const float* b1   = (const float*)d_in[4];
    const float* w2   = (const float*)d_in[5];
    const float* b2   = (const float*)d_in[6];  (void)b2; // cancels in softmax
    const float* wf   = (const float*)d_in[7];
    const float* bfv  = (const float*)d_in[8];
    float* out = (float*)d_out;

    const int n = in_sizes[0] / F;   // 40000
    const int e = in_sizes[1];       // 640000

    ushort_t* abig    = (ushort_t*)d_ws;                   // n*256 bf16 [feat|neigh]
    ushort_t* e_dst   = abig + (size_t)n * 256;            // n*128 bf16
    ushort_t* srcpack = e_dst + (size_t)n * 128;           // n rows x 256 B
    ushort_t* btp     = srcpack + (size_t)n * 128;         // 256*128 bf16 col-major
    ushort_t* btf     = btp + 32768;                       // 128*256 bf16 col-major
    int* row_ptr      = (int*)(btf + 32768);               // n+1

    const int nb0 = (n * 16 + 255) / 256;   // 2500
    const int nb1 = 128, nb2 = 128;
    const int nb3 = (e + 255) / 256;        // 2500

    prep_kernel<<<nb0 + nb1 + nb2 + nb3, 256, 0, stream>>>(
        feat, w1, wf, dst, abig, srcpack, btp, btf, row_ptr, n, e, nb0, nb1, nb2);
    proj_gemm_kernel<<<(n + 63) / 64, 256, 0, stream>>>(
        abig, btp, b1, e_dst, srcpack, n);
    fused_kernel<<<(n + 7) / 8, 256, 0, stream>>>(
        e_dst, srcpack, src, row_ptr, w2, abig, n);
    out_gemm_kernel<<<(n + 63) / 64, 256, 0, stream>>>(abig, btf, bfv, out, n);
}

// Round 7
// 149.941 us; speedup vs baseline: 1.0347x; 1.0347x over previous
//
#include <hip/hip_runtime.h>
#include <math.h>

#define F 128
#define OUT 128

typedef unsigned short ushort_t;
typedef __attribute__((ext_vector_type(8))) short bfrag;   // 8 bf16
typedef __attribute__((ext_vector_type(4))) float ffrag;   // 4 fp32 acc
typedef __attribute__((ext_vector_type(2))) float fx2;     // 2 fp32

__device__ __forceinline__ float bf_lo(unsigned int u) {
    return __uint_as_float(u << 16);
}
__device__ __forceinline__ float bf_hi(unsigned int u) {
    return __uint_as_float(u & 0xffff0000u);
}
__device__ __forceinline__ ushort_t f2bf(float f) {
    unsigned int x = __float_as_uint(f);
    unsigned int r = x + 0x7fffu + ((x >> 16) & 1u);
    return (ushort_t)(r >> 16);
}
__device__ __forceinline__ unsigned pk2(float lo, float hi) {
    return (unsigned)f2bf(lo) | ((unsigned)f2bf(hi) << 16);
}

// DPP rotate-add within a 16-lane row (VALU, no LDS pipe).
#define DPP_ADD(x, ctrl) \
    ((x) + __int_as_float(__builtin_amdgcn_update_dpp( \
        0, __float_as_int(x), (ctrl), 0xf, 0xf, true)))

// ---------------------------------------------------------------------------
// srcpack row layout (256 B per node, interleaved per lane):
//   lane fl (features 4fl..4fl+3) reads ONE uint2 at byte 8*fl:
//     .x = 4 bytes e_src  (e5m2 "bf8"): exp(2*proj_src) features 4fl..4fl+3
//     .y = 4 bytes feat   (e4m3 fp8):   features 4fl..4fl+3
// ---------------------------------------------------------------------------

// ---------------------------------------------------------------------------
// tiny_prep: weights + rowptr only (feat pass folded into proj_gemm).
//  part0: btp[j*128+k] = bf16(B[k][j]), B = [w1[:F] | w1[F:]] cols j=0..255.
//  part1: btf[j*256+k] = bf16(wf[k][j]), j=0..127.
//  part2: rowptr (dst sorted).
// ---------------------------------------------------------------------------
__global__ __launch_bounds__(256) void tiny_prep_kernel(
    const float* __restrict__ w1, const float* __restrict__ wf,
    const int* __restrict__ dst, ushort_t* __restrict__ btp,
    ushort_t* __restrict__ btf, int* __restrict__ row_ptr,
    int n, int e, int nb1, int nb2)
{
    const int b = blockIdx.x, t = threadIdx.x;
    if (b < nb1) {
        int idx = b * 256 + t;                         // 0..32767
        int j = idx >> 7, k = idx & 127;
        float v = (j < F) ? w1[(size_t)k * F + j]
                          : w1[(size_t)(F + k) * F + (j - F)];
        btp[idx] = f2bf(v);
    } else if (b < nb1 + nb2) {
        int idx = (b - nb1) * 256 + t;                 // 0..32767
        int j = idx >> 8, k = idx & 255;
        btf[idx] = f2bf(wf[(size_t)k * F + j]);
    } else {
        int i = (b - nb1 - nb2) * 256 + t;
        if (i >= e) return;
        int d = dst[i];
        int prev = (i == 0) ? -1 : dst[i - 1];
        for (int v = prev + 1; v <= d; ++v) row_ptr[v] = i;
        if (i == e - 1) {
            for (int v = d + 1; v <= n; ++v) row_ptr[v] = e;
        }
    }
}

// ---------------------------------------------------------------------------
// G1 (proj, + folded feat prep): reads feat fp32 directly. Staging converts
// to bf16 in LDS AND writes abig[:, :128] (bf16, for out_gemm) and the fp8
// e4m3 feat slots of srcpack. Then C[n x 256] = feat(bf16) @ btp with
// epilogue exp(2*(c+bias)): cols<128 -> e_dst (+b1) bf16; cols>=128 ->
// srcpack es slots as e5m2 (bf8).
// ---------------------------------------------------------------------------
#define PST 136
__global__ __launch_bounds__(256) void proj_gemm_kernel(
    const float* __restrict__ feat, const ushort_t* __restrict__ btp,
    const float* __restrict__ b1, ushort_t* __restrict__ abig,
    ushort_t* __restrict__ e_dst, ushort_t* __restrict__ srcpack, int n)
{
    __shared__ ushort_t As[64 * PST];        // 17408 B
    __shared__ ushort_t Ep[4][16 * 80];      // 10240 B
    const int t = threadIdx.x;
    const int wv = t >> 6, lane = t & 63;
    const int lm = lane & 15, quad = lane >> 4;
    const int row0 = blockIdx.x * 64, col0 = wv * 64;

    // staging: 64 rows x 128 fp32 -> bf16 LDS + abig + fp8 srcpack slots.
    // 1024 chunks of 8 floats, 4 per thread; 16 threads cover a 512B row.
#pragma unroll
    for (int k = 0; k < 4; ++k) {
        int l = k * 256 + t;
        int r = l >> 4, c = (l & 15) * 8;
        int grow = row0 + r;
        float4 a = make_float4(0.f, 0.f, 0.f, 0.f);
        float4 bb = make_float4(0.f, 0.f, 0.f, 0.f);
        if (grow < n) {
            a = *(const float4*)(feat + (size_t)grow * F + c);
            bb = *(const float4*)(feat + (size_t)grow * F + c + 4);
        }
        unsigned p0 = pk2(a.x, a.y), p1 = pk2(a.z, a.w);
        unsigned p2 = pk2(bb.x, bb.y), p3 = pk2(bb.z, bb.w);
        *(uint4*)(As + r * PST + c) = make_uint4(p0, p1, p2, p3);
        if (grow < n) {
            *(uint4*)(abig + (size_t)grow * 256 + c) = make_uint4(p0, p1, p2, p3);
            unsigned w01 = (unsigned)__builtin_amdgcn_cvt_pk_fp8_f32(a.x, a.y, 0, false);
            w01 = (unsigned)__builtin_amdgcn_cvt_pk_fp8_f32(a.z, a.w, (int)w01, true);
            unsigned w23 = (unsigned)__builtin_amdgcn_cvt_pk_fp8_f32(bb.x, bb.y, 0, false);
            w23 = (unsigned)__builtin_amdgcn_cvt_pk_fp8_f32(bb.z, bb.w, (int)w23, true);
            char* rb = (char*)srcpack + (size_t)grow * 256;
            *(unsigned*)(rb + c * 2 + 4) = w01;
            *(unsigned*)(rb + c * 2 + 12) = w23;
        }
    }
    __syncthreads();

    bfrag bfr[4][4];
#pragma unroll
    for (int ks = 0; ks < 4; ++ks)
#pragma unroll
        for (int ni = 0; ni < 4; ++ni)
            bfr[ks][ni] = *(const bfrag*)(btp + (size_t)(col0 + ni * 16 + lm) * 128
                                          + ks * 32 + quad * 8);

    ffrag acc[4][4];
#pragma unroll
    for (int mi = 0; mi < 4; ++mi)
#pragma unroll
        for (int ni = 0; ni < 4; ++ni) acc[mi][ni] = (ffrag){0.f, 0.f, 0.f, 0.f};

#pragma unroll
    for (int ks = 0; ks < 4; ++ks)
#pragma unroll
        for (int mi = 0; mi < 4; ++mi) {
            bfrag af = *(const bfrag*)(As + (mi * 16 + lm) * PST + ks * 32 + quad * 8);
#pragma unroll
            for (int ni = 0; ni < 4; ++ni)
                acc[mi][ni] = __builtin_amdgcn_mfma_f32_16x16x32_bf16(
                    af, bfr[ks][ni], acc[mi][ni], 0, 0, 0);
        }

    float bias[4];
#pragma unroll
    for (int ni = 0; ni < 4; ++ni)
        bias[ni] = (col0 < F) ? b1[col0 + ni * 16 + lm] : 0.f;

#pragma unroll
    for (int mi = 0; mi < 4; ++mi) {
        // compute-layout write into per-wave patch (conflict-free)
#pragma unroll
        for (int ni = 0; ni < 4; ++ni)
#pragma unroll
            for (int r = 0; r < 4; ++r)
                Ep[wv][(quad * 4 + r) * 80 + ni * 16 + lm] =
                    f2bf(__expf(2.f * (acc[mi][ni][r] + bias[ni])));
        // coalesced read-out: 2 passes x 8 rows x 8 lanes x 16B
#pragma unroll
        for (int ps = 0; ps < 2; ++ps) {
            int rl = ps * 8 + (lane >> 3), co = (lane & 7) * 8;
            uint4 vv = *(const uint4*)(&Ep[wv][rl * 80 + co]);
            int grow = row0 + mi * 16 + rl;
            if (grow < n) {
                if (col0 < F) {
                    *(uint4*)(e_dst + (size_t)grow * F + col0 + co) = vv;
                } else {
                    int f0 = col0 - F + co;   // multiple of 8
                    // es bf16 -> e5m2 (bf8), features f0..f0+3 and f0+4..f0+7
                    unsigned b0 = (unsigned)__builtin_amdgcn_cvt_pk_bf8_f32(
                        bf_lo(vv.x), bf_hi(vv.x), 0, false);
                    b0 = (unsigned)__builtin_amdgcn_cvt_pk_bf8_f32(
                        bf_lo(vv.y), bf_hi(vv.y), (int)b0, true);
                    unsigned b1v = (unsigned)__builtin_amdgcn_cvt_pk_bf8_f32(
                        bf_lo(vv.z), bf_hi(vv.z), 0, false);
                    b1v = (unsigned)__builtin_amdgcn_cvt_pk_bf8_f32(
                        bf_lo(vv.w), bf_hi(vv.w), (int)b1v, true);
                    char* rb = (char*)srcpack + (size_t)grow * 256;
                    *(unsigned*)(rb + f0 * 2) = b0;       // lane f0/4 es slot
                    *(unsigned*)(rb + f0 * 2 + 8) = b1v;  // lane f0/4+1 es slot
                }
            }
        }
    }
}

// ---------------------------------------------------------------------------
// K2: fused score+softmax+aggregate (unchanged from R6, passing at 0.055).
// One 32-lane half-wave per node; per edge ONE uint2 gather per lane
// (256 B/row: es e5m2 + feat e4m3, HW decode). Pair-rcp score, DPP reduce,
// static softmax bound M = b2 + sum|w2|. Writes neigh bf16 to abig[:,128:].
// ---------------------------------------------------------------------------
__global__ __launch_bounds__(256) void fused_kernel(
    const ushort_t* __restrict__ e_dst, const ushort_t* __restrict__ srcpack,
    const int* __restrict__ src, const int* __restrict__ row_ptr,
    const float* __restrict__ w2, ushort_t* __restrict__ abig, int n)
{
    const int v = (int)((blockIdx.x * 256u + threadIdx.x) >> 5);
    const int fl = threadIdx.x & 31;
    const int sbase = threadIdx.x & 32;

    const float4 wv4 = ((const float4*)w2)[fl];
    const float w0 = wv4.x, w1_ = wv4.y, w2_ = wv4.z, w3_ = wv4.w;
    float sw = w0 + w1_ + w2_ + w3_;
    float aw = fabsf(w0) + fabsf(w1_) + fabsf(w2_) + fabsf(w3_);
#pragma unroll
    for (int off = 16; off; off >>= 1) {
        sw += __shfl_xor(sw, off, 64);
        aw += __shfl_xor(aw, off, 64);
    }
    const float K = sw - aw;           // score - M = K - 2*pv  (always <= 0)
    const float L2E = 1.4426950408889634f;
    const float K2 = K * L2E;          // g = exp2(K2 - 2*L2E*p)

    if (v >= n) return;
    const int begin = row_ptr[v], end = row_ptr[v + 1];

    const uint2 ud = *(const uint2*)(e_dst + (size_t)v * F + fl * 4);
    const float ea0 = bf_lo(ud.x), ea1 = bf_hi(ud.x);
    const float ea2 = bf_lo(ud.y), ea3 = bf_hi(ud.y);

    const uint2* __restrict__ sp = (const uint2*)srcpack + fl;  // row = 32 uint2

    float s = 0.f, a0 = 0.f, a1 = 0.f, a2 = 0.f, a3 = 0.f;

    for (int cb = begin; cb < end; cb += 32) {
        const int clen = min(32, end - cb);
        const int sv = (fl < clen) ? src[cb + fl] : 0;
        int jj = 0;
        for (; jj + 4 <= clen; jj += 4) {
            uint2 u[4];
#pragma unroll
            for (int q = 0; q < 4; ++q) {
                const int sq = __shfl(sv, sbase + jj + q, 64);
                u[q] = sp[(size_t)sq * 32];
            }
            float p[4];
#pragma unroll
            for (int q = 0; q < 4; ++q) {
                fx2 eslo = __builtin_amdgcn_cvt_pk_f32_bf8((int)u[q].x, false);
                fx2 eshi = __builtin_amdgcn_cvt_pk_f32_bf8((int)u[q].x, true);
                float A = fmaf(ea0, eslo[0], 1.f);
                float B = fmaf(ea1, eslo[1], 1.f);
                float C = fmaf(ea2, eshi[0], 1.f);
                float D = fmaf(ea3, eshi[1], 1.f);
                float nAB = fmaf(w0, B, w1_ * A);
                float nCD = fmaf(w2_, D, w3_ * C);
                float rAB = __builtin_amdgcn_rcpf(A * B);
                float rCD = __builtin_amdgcn_rcpf(C * D);
                p[q] = fmaf(nAB, rAB, nCD * rCD);
            }
#pragma unroll
            for (int q = 0; q < 4; ++q) {
                p[q] = DPP_ADD(p[q], 0x121);     // row_ror:1
                p[q] = DPP_ADD(p[q], 0x122);     // row_ror:2
                p[q] = DPP_ADD(p[q], 0x124);     // row_ror:4
                p[q] = DPP_ADD(p[q], 0x128);     // row_ror:8
                p[q] += __shfl_xor(p[q], 16, 64);
            }
            float g[4];
#pragma unroll
            for (int q = 0; q < 4; ++q)
                g[q] = exp2f(fmaf(-2.f * L2E, p[q], K2));
            s += (g[0] + g[1]) + (g[2] + g[3]);
#pragma unroll
            for (int q = 0; q < 4; ++q) {
                fx2 lo = __builtin_amdgcn_cvt_pk_f32_fp8((int)u[q].y, false);
                fx2 hi = __builtin_amdgcn_cvt_pk_f32_fp8((int)u[q].y, true);
                a0 = fmaf(g[q], lo[0], a0);
                a1 = fmaf(g[q], lo[1], a1);
                a2 = fmaf(g[q], hi[0], a2);
                a3 = fmaf(g[q], hi[1], a3);
            }
        }
        for (; jj < clen; ++jj) {
            const int s0 = __shfl(sv, sbase + jj, 64);
            const uint2 u0 = sp[(size_t)s0 * 32];
            fx2 eslo = __builtin_amdgcn_cvt_pk_f32_bf8((int)u0.x, false);
            fx2 eshi = __builtin_amdgcn_cvt_pk_f32_bf8((int)u0.x, true);
            float A = fmaf(ea0, eslo[0], 1.f);
            float B = fmaf(ea1, eslo[1], 1.f);
            float C = fmaf(ea2, eshi[0], 1.f);
            float D = fmaf(ea3, eshi[1], 1.f);
            float nAB = fmaf(w0, B, w1_ * A);
            float nCD = fmaf(w2_, D, w3_ * C);
            float rAB = __builtin_amdgcn_rcpf(A * B);
            float rCD = __builtin_amdgcn_rcpf(C * D);
            float p0 = fmaf(nAB, rAB, nCD * rCD);
            p0 = DPP_ADD(p0, 0x121);
            p0 = DPP_ADD(p0, 0x122);
            p0 = DPP_ADD(p0, 0x124);
            p0 = DPP_ADD(p0, 0x128);
            p0 += __shfl_xor(p0, 16, 64);
            const float g0 = exp2f(fmaf(-2.f * L2E, p0, K2));
            s += g0;
            fx2 lo = __builtin_amdgcn_cvt_pk_f32_fp8((int)u0.y, false);
            fx2 hi = __builtin_amdgcn_cvt_pk_f32_fp8((int)u0.y, true);
            a0 = fmaf(g0, lo[0], a0);
            a1 = fmaf(g0, lo[1], a1);
            a2 = fmaf(g0, hi[0], a2);
            a3 = fmaf(g0, hi[1], a3);
        }
    }

    const float inv = (end > begin) ? 1.f / s : 0.f;
    ushort4 o = make_ushort4(f2bf(a0 * inv), f2bf(a1 * inv),
                             f2bf(a2 * inv), f2bf(a3 * inv));
    *(ushort4*)(abig + (size_t)v * 256 + 128 + fl * 4) = o;
}

// ---------------------------------------------------------------------------
// G2 (out): out[n x 128] = abig(bf16, K=256) @ btf + bf.
// Block = 64 rows x 128 cols, 4 waves (wave w: cols 32w..32w+31).
// Epilogue now goes through a per-wave LDS transpose -> fully-coalesced
// float4 stores (8 lanes x 128 B per row), replacing 32 scalar stores.
// ---------------------------------------------------------------------------
#define OST 280
#define EFS 36
__global__ __launch_bounds__(256) void out_gemm_kernel(
    const ushort_t* __restrict__ abig, const ushort_t* __restrict__ btf,
    const float* __restrict__ bfv, float* __restrict__ out, int n)
{
    __shared__ ushort_t As[64 * OST];        // 35840 B
    __shared__ float Ef[4][16 * EFS];        // 9216 B
    const int t = threadIdx.x;
    const int wv = t >> 6, lane = t & 63;
    const int lm = lane & 15, quad = lane >> 4;
    const int row0 = blockIdx.x * 64, col0 = wv * 32;

#pragma unroll
    for (int k = 0; k < 8; ++k) {            // 64 rows x 32 uint4, coalesced
        int l = k * 256 + t;
        int r = l >> 5, ch = l & 31;
        uint4 d = make_uint4(0, 0, 0, 0);
        if (row0 + r < n) d = *(const uint4*)(abig + (size_t)(row0 + r) * 256 + ch * 8);
        *(uint4*)(As + r * OST + ch * 8) = d;
    }
    __syncthreads();

    bfrag bfr[8][2];
#pragma unroll
    for (int ks = 0; ks < 8; ++ks)
#pragma unroll
        for (int ni = 0; ni < 2; ++ni)
            bfr[ks][ni] = *(const bfrag*)(btf + (size_t)(col0 + ni * 16 + lm) * 256
                                          + ks * 32 + quad * 8);

    ffrag acc[4][2];
#pragma unroll
    for (int mi = 0; mi < 4; ++mi)
#pragma unroll
        for (int ni = 0; ni < 2; ++ni) acc[mi][ni] = (ffrag){0.f, 0.f, 0.f, 0.f};

#pragma unroll
    for (int ks = 0; ks < 8; ++ks)
#pragma unroll
        for (int mi = 0; mi < 4; ++mi) {
            bfrag af = *(const bfrag*)(As + (mi * 16 + lm) * OST + ks * 32 + quad * 8);
#pragma unroll
            for (int ni = 0; ni < 2; ++ni)
                acc[mi][ni] = __builtin_amdgcn_mfma_f32_16x16x32_bf16(
                    af, bfr[ks][ni], acc[mi][ni], 0, 0, 0);
        }

    float bb[2];
#pragma unroll
    for (int ni = 0; ni < 2; ++ni) bb[ni] = bfv[col0 + ni * 16 + lm];

#pragma unroll
    for (int mi = 0; mi < 4; ++mi) {
        // compute-layout write into per-wave patch (2-way bank alias = free)
#pragma unroll
        for (int ni = 0; ni < 2; ++ni)
#pragma unroll
            for (int r = 0; r < 4; ++r)
                Ef[wv][(quad * 4 + r) * EFS + ni * 16 + lm] = acc[mi][ni][r] + bb[ni];
        // coalesced read-out: 2 passes x 8 rows x 8 lanes x 16 B (128 B/row)
#pragma unroll
        for (int ps = 0; ps < 2; ++ps) {
            int rl = ps * 8 + (lane >> 3), co = (lane & 7) * 4;
            float4 vv = *(const float4*)(&Ef[wv][rl * EFS + co]);
            int grow = row0 + mi * 16 + rl;
            if (grow < n)
                *(float4*)(out + (size_t)grow * OUT + col0 + co) = vv;
        }
    }
}

// ---------------------------------------------------------------------------
extern "C" void kernel_launch(void* const* d_in, const int* in_sizes, int n_in,
                              void* d_out, int out_size, void* d_ws, size_t ws_size,
                              hipStream_t stream)
{
    const float* feat = (const float*)d_in[0];
    const int*   src  = (const int*)d_in[1];
    const int*   dst  = (const int*)d_in[2];
    const float* w1   = (const float*)d_in[3];
    const float* b1   = (const float*)d_in[4];
    const float* w2   = (const float*)d_in[5];
    const float* b2   = (const float*)d_in[6];  (void)b2; // cancels in softmax
    const float* wf   = (const float*)d_in[7];
    const float* bfv  = (const float*)d_in[8];
    float* out = (float*)d_out;

    const int n = in_sizes[0] / F;   // 40000
    const int e = in_sizes[1];       // 640000

    ushort_t* abig    = (ushort_t*)d_ws;                   // n*256 bf16 [feat|neigh]
    ushort_t* e_dst   = abig + (size_t)n * 256;            // n*128 bf16
    ushort_t* srcpack = e_dst + (size_t)n * 128;           // n rows x 256 B
    ushort_t* btp     = srcpack + (size_t)n * 128;         // 256*128 bf16 col-major
    ushort_t* btf     = btp + 32768;                       // 128*256 bf16 col-major
    int* row_ptr      = (int*)(btf + 32768);               // n+1

    const int nb1 = 128, nb2 = 128;
    const int nb3 = (e + 255) / 256;        // 2500

    tiny_prep_kernel<<<nb1 + nb2 + nb3, 256, 0, stream>>>(
        w1, wf, dst, btp, btf, row_ptr, n, e, nb1, nb2);
    proj_gemm_kernel<<<(n + 63) / 64, 256, 0, stream>>>(
        feat, btp, b1, abig, e_dst, srcpack, n);
    fused_kernel<<<(n + 7) / 8, 256, 0, stream>>>(
        e_dst, srcpack, src, row_ptr, w2, abig, n);
    out_gemm_kernel<<<(n + 63) / 64, 256, 0, stream>>>(abig, btf, bfv, out, n);
}

// Round 8
// 149.404 us; speedup vs baseline: 1.0384x; 1.0036x over previous
//
#include <hip/hip_runtime.h>
#include <math.h>

#define F 128
#define OUT 128

typedef unsigned short ushort_t;
typedef __attribute__((ext_vector_type(8))) short bfrag;   // 8 bf16
typedef __attribute__((ext_vector_type(4))) float ffrag;   // 4 fp32 acc
typedef __attribute__((ext_vector_type(2))) float fx2;     // 2 fp32

__device__ __forceinline__ float bf_lo(unsigned int u) {
    return __uint_as_float(u << 16);
}
__device__ __forceinline__ float bf_hi(unsigned int u) {
    return __uint_as_float(u & 0xffff0000u);
}
__device__ __forceinline__ ushort_t f2bf(float f) {
    unsigned int x = __float_as_uint(f);
    unsigned int r = x + 0x7fffu + ((x >> 16) & 1u);
    return (ushort_t)(r >> 16);
}
__device__ __forceinline__ unsigned pk2(float lo, float hi) {
    return (unsigned)f2bf(lo) | ((unsigned)f2bf(hi) << 16);
}

// DPP rotate-add within a 16-lane row (VALU, no LDS pipe).
#define DPP_ADD(x, ctrl) \
    ((x) + __int_as_float(__builtin_amdgcn_update_dpp( \
        0, __float_as_int(x), (ctrl), 0xf, 0xf, true)))

// ---------------------------------------------------------------------------
// srcpack row layout (256 B per node): slot j (8 B, j=0..31) holds
//   .x = es  (e5m2 "bf8") features 4j..4j+3,  .y = feat (e4m3) 4j..4j+3.
// A 16-lane row reads one uint4 per lane: lane fl -> slots 2fl,2fl+1 =
//   {es 8fl..+3, feat 8fl..+3, es 8fl+4..+7, feat 8fl+4..+7}.
// ---------------------------------------------------------------------------

// ---------------------------------------------------------------------------
// tiny_prep: weights + rowptr only.
// ---------------------------------------------------------------------------
__global__ __launch_bounds__(256) void tiny_prep_kernel(
    const float* __restrict__ w1, const float* __restrict__ wf,
    const int* __restrict__ dst, ushort_t* __restrict__ btp,
    ushort_t* __restrict__ btf, int* __restrict__ row_ptr,
    int n, int e, int nb1, int nb2)
{
    const int b = blockIdx.x, t = threadIdx.x;
    if (b < nb1) {
        int idx = b * 256 + t;                         // 0..32767
        int j = idx >> 7, k = idx & 127;
        float v = (j < F) ? w1[(size_t)k * F + j]
                          : w1[(size_t)(F + k) * F + (j - F)];
        btp[idx] = f2bf(v);
    } else if (b < nb1 + nb2) {
        int idx = (b - nb1) * 256 + t;                 // 0..32767
        int j = idx >> 8, k = idx & 255;
        btf[idx] = f2bf(wf[(size_t)k * F + j]);
    } else {
        int i = (b - nb1 - nb2) * 256 + t;
        if (i >= e) return;
        int d = dst[i];
        int prev = (i == 0) ? -1 : dst[i - 1];
        for (int v = prev + 1; v <= d; ++v) row_ptr[v] = i;
        if (i == e - 1) {
            for (int v = d + 1; v <= n; ++v) row_ptr[v] = e;
        }
    }
}

// ---------------------------------------------------------------------------
// G1 (proj, + folded feat prep): reads feat fp32 directly. Staging converts
// to bf16 in LDS AND writes abig[:, :128] (bf16) and the fp8 e4m3 feat slots
// of srcpack. Then C = feat(bf16) @ btp with epilogue exp(2*(c+bias)):
// cols<128 -> e_dst (+b1) bf16; cols>=128 -> srcpack es slots as e5m2.
// ---------------------------------------------------------------------------
#define PST 136
__global__ __launch_bounds__(256) void proj_gemm_kernel(
    const float* __restrict__ feat, const ushort_t* __restrict__ btp,
    const float* __restrict__ b1, ushort_t* __restrict__ abig,
    ushort_t* __restrict__ e_dst, ushort_t* __restrict__ srcpack, int n)
{
    __shared__ ushort_t As[64 * PST];        // 17408 B
    __shared__ ushort_t Ep[4][16 * 80];      // 10240 B
    const int t = threadIdx.x;
    const int wv = t >> 6, lane = t & 63;
    const int lm = lane & 15, quad = lane >> 4;
    const int row0 = blockIdx.x * 64, col0 = wv * 64;

#pragma unroll
    for (int k = 0; k < 4; ++k) {
        int l = k * 256 + t;
        int r = l >> 4, c = (l & 15) * 8;
        int grow = row0 + r;
        float4 a = make_float4(0.f, 0.f, 0.f, 0.f);
        float4 bb = make_float4(0.f, 0.f, 0.f, 0.f);
        if (grow < n) {
            a = *(const float4*)(feat + (size_t)grow * F + c);
            bb = *(const float4*)(feat + (size_t)grow * F + c + 4);
        }
        unsigned p0 = pk2(a.x, a.y), p1 = pk2(a.z, a.w);
        unsigned p2 = pk2(bb.x, bb.y), p3 = pk2(bb.z, bb.w);
        *(uint4*)(As + r * PST + c) = make_uint4(p0, p1, p2, p3);
        if (grow < n) {
            *(uint4*)(abig + (size_t)grow * 256 + c) = make_uint4(p0, p1, p2, p3);
            unsigned w01 = (unsigned)__builtin_amdgcn_cvt_pk_fp8_f32(a.x, a.y, 0, false);
            w01 = (unsigned)__builtin_amdgcn_cvt_pk_fp8_f32(a.z, a.w, (int)w01, true);
            unsigned w23 = (unsigned)__builtin_amdgcn_cvt_pk_fp8_f32(bb.x, bb.y, 0, false);
            w23 = (unsigned)__builtin_amdgcn_cvt_pk_fp8_f32(bb.z, bb.w, (int)w23, true);
            char* rb = (char*)srcpack + (size_t)grow * 256;
            *(unsigned*)(rb + c * 2 + 4) = w01;
            *(unsigned*)(rb + c * 2 + 12) = w23;
        }
    }
    __syncthreads();

    bfrag bfr[4][4];
#pragma unroll
    for (int ks = 0; ks < 4; ++ks)
#pragma unroll
        for (int ni = 0; ni < 4; ++ni)
            bfr[ks][ni] = *(const bfrag*)(btp + (size_t)(col0 + ni * 16 + lm) * 128
                                          + ks * 32 + quad * 8);

    ffrag acc[4][4];
#pragma unroll
    for (int mi = 0; mi < 4; ++mi)
#pragma unroll
        for (int ni = 0; ni < 4; ++ni) acc[mi][ni] = (ffrag){0.f, 0.f, 0.f, 0.f};

#pragma unroll
    for (int ks = 0; ks < 4; ++ks)
#pragma unroll
        for (int mi = 0; mi < 4; ++mi) {
            bfrag af = *(const bfrag*)(As + (mi * 16 + lm) * PST + ks * 32 + quad * 8);
#pragma unroll
            for (int ni = 0; ni < 4; ++ni)
                acc[mi][ni] = __builtin_amdgcn_mfma_f32_16x16x32_bf16(
                    af, bfr[ks][ni], acc[mi][ni], 0, 0, 0);
        }

    float bias[4];
#pragma unroll
    for (int ni = 0; ni < 4; ++ni)
        bias[ni] = (col0 < F) ? b1[col0 + ni * 16 + lm] : 0.f;

#pragma unroll
    for (int mi = 0; mi < 4; ++mi) {
#pragma unroll
        for (int ni = 0; ni < 4; ++ni)
#pragma unroll
            for (int r = 0; r < 4; ++r)
                Ep[wv][(quad * 4 + r) * 80 + ni * 16 + lm] =
                    f2bf(__expf(2.f * (acc[mi][ni][r] + bias[ni])));
#pragma unroll
        for (int ps = 0; ps < 2; ++ps) {
            int rl = ps * 8 + (lane >> 3), co = (lane & 7) * 8;
            uint4 vv = *(const uint4*)(&Ep[wv][rl * 80 + co]);
            int grow = row0 + mi * 16 + rl;
            if (grow < n) {
                if (col0 < F) {
                    *(uint4*)(e_dst + (size_t)grow * F + col0 + co) = vv;
                } else {
                    int f0 = col0 - F + co;   // multiple of 8
                    unsigned b0 = (unsigned)__builtin_amdgcn_cvt_pk_bf8_f32(
                        bf_lo(vv.x), bf_hi(vv.x), 0, false);
                    b0 = (unsigned)__builtin_amdgcn_cvt_pk_bf8_f32(
                        bf_lo(vv.y), bf_hi(vv.y), (int)b0, true);
                    unsigned b1v = (unsigned)__builtin_amdgcn_cvt_pk_bf8_f32(
                        bf_lo(vv.z), bf_hi(vv.z), 0, false);
                    b1v = (unsigned)__builtin_amdgcn_cvt_pk_bf8_f32(
                        bf_lo(vv.w), bf_hi(vv.w), (int)b1v, true);
                    char* rb = (char*)srcpack + (size_t)grow * 256;
                    *(unsigned*)(rb + f0 * 2) = b0;
                    *(unsigned*)(rb + f0 * 2 + 8) = b1v;
                }
            }
        }
    }
}

// ---------------------------------------------------------------------------
// K2: fused score+softmax+aggregate, ONE EDGE PER 16-LANE ROW.
// Wave = 1 node; its 4 rows process 4 edges/iteration. Lane covers 8
// features -> one uint4 gather (256 B/row total, unchanged bytes). Row
// reduce = pure DPP row_ror (VALU) — NO LDS-pipe ops in the edge loop;
// src index is a row-uniform VMEM load. Cross-row combine (s, a0..a7) once
// per node via shfl_xor 16/32. Static softmax bound M = b2 + sum|w2|.
// Writes neigh bf16 to abig[:, 128:].
// ---------------------------------------------------------------------------
__global__ __launch_bounds__(256) void fused_kernel(
    const ushort_t* __restrict__ e_dst, const ushort_t* __restrict__ srcpack,
    const int* __restrict__ src, const int* __restrict__ row_ptr,
    const float* __restrict__ w2, ushort_t* __restrict__ abig, int n)
{
    const int v = (int)(blockIdx.x * 4u + (threadIdx.x >> 6));
    const int flane = threadIdx.x & 15;
    const int row = (threadIdx.x >> 4) & 3;

    const float4 wa = ((const float4*)w2)[2 * flane];
    const float4 wb = ((const float4*)w2)[2 * flane + 1];
    float sw = (wa.x + wa.y + wa.z + wa.w) + (wb.x + wb.y + wb.z + wb.w);
    float aw = fabsf(wa.x) + fabsf(wa.y) + fabsf(wa.z) + fabsf(wa.w)
             + fabsf(wb.x) + fabsf(wb.y) + fabsf(wb.z) + fabsf(wb.w);
#pragma unroll
    for (int off = 8; off; off >>= 1) {     // within-row reduce (16 lanes)
        sw += __shfl_xor(sw, off, 64);
        aw += __shfl_xor(aw, off, 64);
    }
    const float L2E = 1.4426950408889634f;
    const float K2 = (sw - aw) * L2E;       // g = exp2(K2 - 2*L2E*p)

    if (v >= n) return;
    const int begin = row_ptr[v], end = row_ptr[v + 1];

    const uint4 ud = *(const uint4*)(e_dst + (size_t)v * F + flane * 8);
    const float ea0 = bf_lo(ud.x), ea1 = bf_hi(ud.x);
    const float ea2 = bf_lo(ud.y), ea3 = bf_hi(ud.y);
    const float ea4 = bf_lo(ud.z), ea5 = bf_hi(ud.z);
    const float ea6 = bf_lo(ud.w), ea7 = bf_hi(ud.w);

    const uint4* __restrict__ sp = (const uint4*)srcpack;   // 16 uint4 / row

    float s = 0.f;
    float a0 = 0.f, a1 = 0.f, a2 = 0.f, a3 = 0.f;
    float a4 = 0.f, a5 = 0.f, a6 = 0.f, a7 = 0.f;

    for (int cb = begin; cb < end; cb += 4) {
        const int ed = cb + row;
        const bool valid = ed < end;
        const int sq = src[valid ? ed : end - 1];   // row-uniform load
        const uint4 u = sp[(size_t)sq * 16 + flane];
        fx2 e01 = __builtin_amdgcn_cvt_pk_f32_bf8((int)u.x, false);
        fx2 e23 = __builtin_amdgcn_cvt_pk_f32_bf8((int)u.x, true);
        fx2 e45 = __builtin_amdgcn_cvt_pk_f32_bf8((int)u.z, false);
        fx2 e67 = __builtin_amdgcn_cvt_pk_f32_bf8((int)u.z, true);
        float A = fmaf(ea0, e01[0], 1.f), B = fmaf(ea1, e01[1], 1.f);
        float C = fmaf(ea2, e23[0], 1.f), D = fmaf(ea3, e23[1], 1.f);
        float E = fmaf(ea4, e45[0], 1.f), G = fmaf(ea5, e45[1], 1.f);
        float H = fmaf(ea6, e67[0], 1.f), I = fmaf(ea7, e67[1], 1.f);
        float p;
        p = fmaf(wa.x, B, wa.y * A) * __builtin_amdgcn_rcpf(A * B);
        p = fmaf(fmaf(wa.z, D, wa.w * C), __builtin_amdgcn_rcpf(C * D), p);
        p = fmaf(fmaf(wb.x, G, wb.y * E), __builtin_amdgcn_rcpf(E * G), p);
        p = fmaf(fmaf(wb.z, I, wb.w * H), __builtin_amdgcn_rcpf(H * I), p);
        p = DPP_ADD(p, 0x121);              // row_ror:1
        p = DPP_ADD(p, 0x122);              // row_ror:2
        p = DPP_ADD(p, 0x124);              // row_ror:4
        p = DPP_ADD(p, 0x128);              // row_ror:8
        const float g = valid ? exp2f(fmaf(-2.f * L2E, p, K2)) : 0.f;
        s += g;
        fx2 f01 = __builtin_amdgcn_cvt_pk_f32_fp8((int)u.y, false);
        fx2 f23 = __builtin_amdgcn_cvt_pk_f32_fp8((int)u.y, true);
        fx2 f45 = __builtin_amdgcn_cvt_pk_f32_fp8((int)u.w, false);
        fx2 f67 = __builtin_amdgcn_cvt_pk_f32_fp8((int)u.w, true);
        a0 = fmaf(g, f01[0], a0); a1 = fmaf(g, f01[1], a1);
        a2 = fmaf(g, f23[0], a2); a3 = fmaf(g, f23[1], a3);
        a4 = fmaf(g, f45[0], a4); a5 = fmaf(g, f45[1], a5);
        a6 = fmaf(g, f67[0], a6); a7 = fmaf(g, f67[1], a7);
    }

    // cross-row combine (once per node)
    s += __shfl_xor(s, 16, 64);  s += __shfl_xor(s, 32, 64);
    a0 += __shfl_xor(a0, 16, 64); a0 += __shfl_xor(a0, 32, 64);
    a1 += __shfl_xor(a1, 16, 64); a1 += __shfl_xor(a1, 32, 64);
    a2 += __shfl_xor(a2, 16, 64); a2 += __shfl_xor(a2, 32, 64);
    a3 += __shfl_xor(a3, 16, 64); a3 += __shfl_xor(a3, 32, 64);
    a4 += __shfl_xor(a4, 16, 64); a4 += __shfl_xor(a4, 32, 64);
    a5 += __shfl_xor(a5, 16, 64); a5 += __shfl_xor(a5, 32, 64);
    a6 += __shfl_xor(a6, 16, 64); a6 += __shfl_xor(a6, 32, 64);
    a7 += __shfl_xor(a7, 16, 64); a7 += __shfl_xor(a7, 32, 64);

    const float inv = (end > begin) ? 1.f / s : 0.f;
    if (row == 0) {
        uint4 o = make_uint4(pk2(a0 * inv, a1 * inv), pk2(a2 * inv, a3 * inv),
                             pk2(a4 * inv, a5 * inv), pk2(a6 * inv, a7 * inv));
        *(uint4*)(abig + (size_t)v * 256 + 128 + flane * 8) = o;
    }
}

// ---------------------------------------------------------------------------
// G2 (out): out[n x 128] = abig(bf16, K=256) @ btf + bf.
// LDS-transpose epilogue -> fully-coalesced float4 stores.
// ---------------------------------------------------------------------------
#define OST 280
#define EFS 36
__global__ __launch_bounds__(256) void out_gemm_kernel(
    const ushort_t* __restrict__ abig, const ushort_t* __restrict__ btf,
    const float* __restrict__ bfv, float* __restrict__ out, int n)
{
    __shared__ ushort_t As[64 * OST];        // 35840 B
    __shared__ float Ef[4][16 * EFS];        // 9216 B
    const int t = threadIdx.x;
    const int wv = t >> 6, lane = t & 63;
    const int lm = lane & 15, quad = lane >> 4;
    const int row0 = blockIdx.x * 64, col0 = wv * 32;

#pragma unroll
    for (int k = 0; k < 8; ++k) {
        int l = k * 256 + t;
        int r = l >> 5, ch = l & 31;
        uint4 d = make_uint4(0, 0, 0, 0);
        if (row0 + r < n) d = *(const uint4*)(abig + (size_t)(row0 + r) * 256 + ch * 8);
        *(uint4*)(As + r * OST + ch * 8) = d;
    }
    __syncthreads();

    bfrag bfr[8][2];
#pragma unroll
    for (int ks = 0; ks < 8; ++ks)
#pragma unroll
        for (int ni = 0; ni < 2; ++ni)
            bfr[ks][ni] = *(const bfrag*)(btf + (size_t)(col0 + ni * 16 + lm) * 256
                                          + ks * 32 + quad * 8);

    ffrag acc[4][2];
#pragma unroll
    for (int mi = 0; mi < 4; ++mi)
#pragma unroll
        for (int ni = 0; ni < 2; ++ni) acc[mi][ni] = (ffrag){0.f, 0.f, 0.f, 0.f};

#pragma unroll
    for (int ks = 0; ks < 8; ++ks)
#pragma unroll
        for (int mi = 0; mi < 4; ++mi) {
            bfrag af = *(const bfrag*)(As + (mi * 16 + lm) * OST + ks * 32 + quad * 8);
#pragma unroll
            for (int ni = 0; ni < 2; ++ni)
                acc[mi][ni] = __builtin_amdgcn_mfma_f32_16x16x32_bf16(
                    af, bfr[ks][ni], acc[mi][ni], 0, 0, 0);
        }

    float bb[2];
#pragma unroll
    for (int ni = 0; ni < 2; ++ni) bb[ni] = bfv[col0 + ni * 16 + lm];

#pragma unroll
    for (int mi = 0; mi < 4; ++mi) {
#pragma unroll
        for (int ni = 0; ni < 2; ++ni)
#pragma unroll
            for (int r = 0; r < 4; ++r)
                Ef[wv][(quad * 4 + r) * EFS + ni * 16 + lm] = acc[mi][ni][r] + bb[ni];
#pragma unroll
        for (int ps = 0; ps < 2; ++ps) {
            int rl = ps * 8 + (lane >> 3), co = (lane & 7) * 4;
            float4 vv = *(const float4*)(&Ef[wv][rl * EFS + co]);
            int grow = row0 + mi * 16 + rl;
            if (grow < n)
                *(float4*)(out + (size_t)grow * OUT + col0 + co) = vv;
        }
    }
}

// ---------------------------------------------------------------------------
extern "C" void kernel_launch(void* const* d_in, const int* in_sizes, int n_in,
                              void* d_out, int out_size, void* d_ws, size_t ws_size,
                              hipStream_t stream)
{
    const float* feat = (const float*)d_in[0];
    const int*   src  = (const int*)d_in[1];
    const int*   dst  = (const int*)d_in[2];
    const float* w1   = (const float*)d_in[3];
    const float* b1   = (const float*)d_in[4];
    const float* w2   = (const float*)d_in[5];
    const float* b2   = (const float*)d_in[6];  (void)b2; // cancels in softmax
    const float* wf   = (const float*)d_in[7];
    const float* bfv  = (const float*)d_in[8];
    float* out = (float*)d_out;

    const int n = in_sizes[0] / F;   // 40000
    const int e = in_sizes[1];       // 640000

    ushort_t* abig    = (ushort_t*)d_ws;                   // n*256 bf16 [feat|neigh]
    ushort_t* e_dst   = abig + (size_t)n * 256;            // n*128 bf16
    ushort_t* srcpack = e_dst + (size_t)n * 128;           // n rows x 256 B
    ushort_t* btp     = srcpack + (size_t)n * 128;         // 256*128 bf16 col-major
    ushort_t* btf     = btp + 32768;                       // 128*256 bf16 col-major
    int* row_ptr      = (int*)(btf + 32768);               // n+1

    const int nb1 = 128, nb2 = 128;
    const int nb3 = (e + 255) / 256;        // 2500

    tiny_prep_kernel<<<nb1 + nb2 + nb3, 256, 0, stream>>>(
        w1, wf, dst, btp, btf, row_ptr, n, e, nb1, nb2);
    proj_gemm_kernel<<<(n + 63) / 64, 256, 0, stream>>>(
        feat, btp, b1, abig, e_dst, srcpack, n);
    fused_kernel<<<(n + 3) / 4, 256, 0, stream>>>(
        e_dst, srcpack, src, row_ptr, w2, abig, n);
    out_gemm_kernel<<<(n + 63) / 64, 256, 0, stream>>>(abig, btf, bfv, out, n);
}